// Round 3
// baseline (122.938 us; speedup 1.0000x reference)
//
#include <hip/hip_runtime.h>
#include <hip/hip_bf16.h>

#define VOCAB 10000
#define EMB   16
#define HID   32
#define BATCH 4096
#define TLEN  512

// ---------------------------------------------------------------------------
// Kernel 1: P[v][j] = b[j] + sum_e emb[v][e] * Wx[e][j]   (fp32 table in ws)
// 10000 x 32 threads, 16 FMAs each. All inputs fp32.
// ---------------------------------------------------------------------------
__global__ __launch_bounds__(256) void rnn_proj(
    const float* __restrict__ emb, const float* __restrict__ Wx,
    const float* __restrict__ bias, float* __restrict__ P)
{
    int tid = blockIdx.x * 256 + threadIdx.x;
    if (tid >= VOCAB * HID) return;
    int v = tid >> 5;
    int j = tid & 31;
    float acc = bias[j];
    const float* ev = emb + v * EMB;
#pragma unroll
    for (int e = 0; e < EMB; ++e) {
        acc = fmaf(ev[e], Wx[e * HID + j], acc);
    }
    P[tid] = acc;
}

// ---------------------------------------------------------------------------
// Kernel 2: the scan. Wave = 2 batches x 32 j-lanes. Wh column j in VGPRs.
// h (fp32) in wave-private LDS rows (broadcast float4 reads, no barriers).
// Tokens prefetched 3 steps ahead, P rows 2 steps ahead.
// ---------------------------------------------------------------------------
__global__ __launch_bounds__(256) void rnn_scan(
    const int*   __restrict__ x,   const float* __restrict__ P,
    const float* __restrict__ Wh,  const float* __restrict__ Wd,
    const float* __restrict__ bd,  float* __restrict__ out)
{
    __shared__ float h_lds[8][HID];

    const int lane = threadIdx.x & 63;
    const int wave = threadIdx.x >> 6;
    const int half = lane >> 5;
    const int j    = lane & 31;
    const int hb   = wave * 2 + half;          // 0..7 (wave-private row)
    const int b    = blockIdx.x * 8 + hb;

    // Wh column j -> 32 VGPRs:  z_j = sum_i h_i * Wh[i][j]
    float whc[HID];
#pragma unroll
    for (int i = 0; i < HID; ++i) whc[i] = Wh[i * HID + j];

    h_lds[hb][j] = 0.0f;                        // h0 = 0 (wave-private, no barrier)

    const int* xb = x + b * TLEN;

    // software pipeline: pA = P(t), pB = P(t+1), tokN = token(t+2)
    int   tokN = xb[2];
    float pA = P[xb[0] * HID + j];
    float pB = P[xb[1] * HID + j];

    float hj = 0.0f;
    const float TWO_LOG2E = 2.8853900817779268f; // 2*log2(e)

    for (int t = 0; t < TLEN; ++t) {
        // prefetch token(t+3); issue P(t+2) using token loaded last iteration
        int   tokN2 = (t + 3 < TLEN) ? xb[t + 3] : 0;
        float pC    = P[tokN * HID + j];

        // gather h row (broadcast reads, uniform address per half-wave)
        float hbuf[HID];
#pragma unroll
        for (int q = 0; q < 8; ++q) {
            float4 hv = ((const float4*)h_lds[hb])[q];
            hbuf[4*q+0] = hv.x; hbuf[4*q+1] = hv.y;
            hbuf[4*q+2] = hv.z; hbuf[4*q+3] = hv.w;
        }

        float a0 = pA, a1 = 0.f, a2 = 0.f, a3 = 0.f;
#pragma unroll
        for (int i = 0; i < HID; i += 4) {
            a0 = fmaf(hbuf[i+0], whc[i+0], a0);
            a1 = fmaf(hbuf[i+1], whc[i+1], a1);
            a2 = fmaf(hbuf[i+2], whc[i+2], a2);
            a3 = fmaf(hbuf[i+3], whc[i+3], a3);
        }
        float z = (a0 + a1) + (a2 + a3);

        // tanh(z) = (e^{2z}-1)/(e^{2z}+1), e^{2z} = 2^{z*2*log2e}
        z = fminf(fmaxf(z, -10.0f), 10.0f);     // saturated anyway; keeps exp2 in range
        float e2 = __builtin_amdgcn_exp2f(z * TWO_LOG2E);
        hj = (e2 - 1.0f) * __builtin_amdgcn_rcpf(e2 + 1.0f);

        h_lds[hb][j] = hj;                      // visible to this wave next iter

        pA = pB; pB = pC; tokN = tokN2;
    }

    // out[b] = sigmoid(sum_j h_j * Wd[j] + bd)
    float s = hj * Wd[j];
#pragma unroll
    for (int off = 16; off > 0; off >>= 1)
        s += __shfl_xor(s, off, 32);            // reduce within 32-lane half
    if (j == 0) {
        float logit = s + bd[0];
        float o = 1.0f / (1.0f + __expf(-logit));
        out[b] = o;                             // fp32 output
    }
}

// ---------------------------------------------------------------------------
extern "C" void kernel_launch(void* const* d_in, const int* in_sizes, int n_in,
                              void* d_out, int out_size, void* d_ws, size_t ws_size,
                              hipStream_t stream)
{
    const int*   x   = (const int*)  d_in[0];
    const float* emb = (const float*)d_in[1];
    const float* Wx  = (const float*)d_in[2];
    const float* Wh  = (const float*)d_in[3];
    const float* bia = (const float*)d_in[4];
    const float* Wd  = (const float*)d_in[5];
    const float* bd  = (const float*)d_in[6];
    float* out = (float*)d_out;

    float* P = (float*)d_ws;                    // VOCAB*HID*4 = 1.28 MB

    rnn_proj<<<(VOCAB * HID + 255) / 256, 256, 0, stream>>>(emb, Wx, bia, P);
    rnn_scan<<<BATCH / 8, 256, 0, stream>>>(x, P, Wh, Wd, bd, out);
}